// Round 7
// baseline (107.881 us; speedup 1.0000x reference)
//
#include <hip/hip_runtime.h>

// (T,B,C)=(2048,2,1024), weight (H,1,K)=(16,1,31), P=15.
// R7 = R6 resubmit (container died before benching).
//   - blocks 0..511:  depthwise conv tiles (out, 16.8 MB) — retire early
//   - blocks 512..767: 256 sweep blocks (1 per CU) fill the 512 MiB banded
//     Toeplitz in fillBufferAligned's pattern: grid-stride, dense 1 MiB
//     window, plain dwordx4 stores, band values inline (rare branch).
// Theory: 6.6 TB/s writes need FEW streams (~1 block/CU); our 2560-block
// writers all plateaued at ~5.2-5.4 TB/s (DRAM row thrash).
#define T_DIM 2048
#define B_DIM 2
#define C_DIM 1024
#define H_DIM 16
#define K_DIM 31
#define P_PAD 15
#define BC    (B_DIM * C_DIM)     // 2048 columns, contiguous for fixed t
#define TT    32                  // t-tile per conv thread

#define CONV_BLOCKS  512          // (BC/256) * (T_DIM/TT) = 8*64 tiles
#define SWEEP_BLOCKS 256          // ~1 per CU, like fillBufferAligned
#define GRID_BLKS    (CONV_BLOCKS + SWEEP_BLOCKS)
#define N4_TOTAL     33554432u    // 32*T*T/4 float4s (512 MiB)
#define SWEEP_STRIDE (SWEEP_BLOCKS * 256u)        // 65536 f4 = 1 MiB window
#define SWEEP_ITERS  (N4_TOTAL / SWEEP_STRIDE)    // 512, exact

typedef float v4f __attribute__((ext_vector_type(4)));

__global__ __launch_bounds__(256) void k_fused(const float* __restrict__ x,
                                               const float* __restrict__ w,
                                               float* __restrict__ out,
                                               float* __restrict__ we) {
    __shared__ float lw[H_DIM * K_DIM];       // softmaxed weights, all heads
    const int tid = threadIdx.x;

    // ---- per-block softmax (threads 0..15, one head each; ~free) ----
    if (tid < H_DIM) {
        float v[K_DIM];
        float m = -1e30f;
#pragma unroll
        for (int k = 0; k < K_DIM; ++k) { v[k] = w[tid * K_DIM + k]; m = fmaxf(m, v[k]); }
        float s = 0.f;
#pragma unroll
        for (int k = 0; k < K_DIM; ++k) { v[k] = expf(v[k] - m); s += v[k]; }
        float inv = 1.f / s;
#pragma unroll
        for (int k = 0; k < K_DIM; ++k) lw[tid * K_DIM + k] = v[k] * inv;
    }
    __syncthreads();

    const int bid = blockIdx.x;

    if (bid < CONV_BLOCKS) {
        // ---- depthwise conv tile: out[t,col] = sum_k w[h,k] x[t-P+k,col] ----
        const int colBase = (bid & 7) * 256;
        const int t0      = (bid >> 3) * TT;
        const int col     = colBase + tid;
        const int h       = (col & (C_DIM - 1)) >> 6;   // R=64; wave-uniform

        float wr[K_DIM];
#pragma unroll
        for (int k = 0; k < K_DIM; ++k) wr[k] = lw[h * K_DIM + k];

        float xv[TT + K_DIM - 1];                       // 62-value sliding window
#pragma unroll
        for (int r = 0; r < TT + K_DIM - 1; ++r) {
            int t = t0 - P_PAD + r;                     // wave-uniform bounds
            xv[r] = (t >= 0 && t < T_DIM) ? x[t * BC + col] : 0.f;
        }
#pragma unroll
        for (int i = 0; i < TT; ++i) {
            float acc = 0.f;
#pragma unroll
            for (int k = 0; k < K_DIM; ++k) acc = fmaf(wr[k], xv[i + k], acc);
            out[(t0 + i) * BC + col] = acc;
        }
    } else {
        // ---- zero+band sweep: fillBufferAligned access structure ----
        // we[bh,i,j] = (0 <= j-i+P < K) ? lw[bh&15, j-i+P] : 0
        const unsigned f0 = (unsigned)(bid - CONV_BLOCKS) * 256u + (unsigned)tid;
        v4f* we4 = (v4f*)we;
#pragma unroll 4
        for (unsigned it = 0; it < SWEEP_ITERS; ++it) {
            const unsigned f   = it * SWEEP_STRIDE + f0;   // float4 index
            const unsigned row = f >> 9;                   // 512 f4 per row
            const int      i   = (int)(row & (T_DIM - 1));
            const int      d0  = (int)((f & 511u) << 2) - i + P_PAD;

            v4f v = (v4f)0.f;
            if (d0 >= -3 && d0 <= 30) {                    // rare (~2% of waves)
                const float* wrow = lw + ((row >> 11) & (H_DIM - 1)) * K_DIM;
                v.x = (d0     >= 0) ? wrow[d0]     : 0.f;  // d0 <= 30 given
                v.y = (d0 + 1 >= 0 && d0 + 1 < K_DIM) ? wrow[d0 + 1] : 0.f;
                v.z = (d0 + 2 >= 0 && d0 + 2 < K_DIM) ? wrow[d0 + 2] : 0.f;
                v.w = (d0 + 3 >= 0 && d0 + 3 < K_DIM) ? wrow[d0 + 3] : 0.f;
            }
            we4[f] = v;                                    // plain store via L2
        }
    }
}

extern "C" void kernel_launch(void* const* d_in, const int* in_sizes, int n_in,
                              void* d_out, int out_size, void* d_ws, size_t ws_size,
                              hipStream_t stream) {
    const float* x = (const float*)d_in[0];
    const float* w = (const float*)d_in[1];
    float* out = (float*)d_out;                          // (T,B,C) first
    float* we  = out + (size_t)T_DIM * B_DIM * C_DIM;    // then (B*H,T,T)

    k_fused<<<GRID_BLKS, 256, 0, stream>>>(x, w, out, we);
}